// Round 1
// baseline (117.054 us; speedup 1.0000x reference)
//
#include <hip/hip_runtime.h>
#include <hip/hip_bf16.h>
#include <math.h>

// PhaseMLP: y = MLP with Catmull-Rom phase-interpolated weights.
// Key identity: interp-then-matmul == 4 GEMMs combined with per-sample coeffs:
//   y[b,o] = sum_k c_k(b) * sum_i x[b,i] * W[k,i,o]
//          = sum_{k,i} (c_k(b)*x[b,i]) * Wflat[k*K+i, o]
// So each layer is ONE bf16 GEMM with a c-scaled A matrix (built in the
// previous layer's epilogue) against the naturally-flattened weights.

typedef __attribute__((ext_vector_type(8))) short bf16x8;
typedef __attribute__((ext_vector_type(4))) float f32x4;

static __device__ __forceinline__ unsigned short f2bf(float f) {
  union { float f; unsigned int u; } v; v.f = f;
  unsigned int r = v.u + 0x7fffu + ((v.u >> 16) & 1u); // RNE
  return (unsigned short)(r >> 16);
}

// ---------------------------------------------------------------------------
// Kernel 1: per-sample Catmull-Rom coeffs (absolute-index order) + A0 build.
// A0[b, k*128+i] = bf16(c_k(b) * x[b,i])
// ---------------------------------------------------------------------------
__global__ void k_build_a0(const float* __restrict__ x, const float* __restrict__ phase,
                           float* __restrict__ c, unsigned short* __restrict__ A0) {
  int b = blockIdx.x;       // 4096
  int i = threadIdx.x;      // 128
  float t = 4.0f * phase[b];
  float ft = floorf(t);
  int i1 = ((int)ft) & 3;   // floor(t) in [0,3] for phase in [0,1)
  float w = t - ft;
  float w2 = w * w, w3 = w2 * w;
  // basis coeffs for anchors a0..a3 (relative order)
  float c0 = -0.5f * w + w2 - 0.5f * w3;
  float c1 = 1.0f - 2.5f * w2 + 1.5f * w3;
  float c2 = 0.5f * w + 2.0f * w2 - 1.5f * w3;
  float c3 = -0.5f * w2 + 0.5f * w3;
  float cabs[4];
  cabs[(i1 + 3) & 3] = c0;  // i0 = i1-1 mod 4
  cabs[i1]           = c1;
  cabs[(i1 + 1) & 3] = c2;
  cabs[(i1 + 2) & 3] = c3;
  float xv = x[b * 128 + i];
#pragma unroll
  for (int k = 0; k < 4; ++k)
    A0[(size_t)b * 512 + k * 128 + i] = f2bf(cabs[k] * xv);
  if (i < 4) c[b * 4 + i] = cabs[i];
}

// ---------------------------------------------------------------------------
// Kernel 2: transpose+convert all three weight tensors in one launch.
// In:  W_l as fp32 [4*K, O] (natural flatten of (4,K,O))
// Out: Wt_l as bf16 [O, 4*K]  (rows contiguous in k' -> ds_read_b128-able)
// ---------------------------------------------------------------------------
__global__ void k_wt_all(const float* __restrict__ w0, const float* __restrict__ w1,
                         const float* __restrict__ w2, unsigned short* __restrict__ t0,
                         unsigned short* __restrict__ t1, unsigned short* __restrict__ t2) {
  __shared__ float tile[32][33];
  int bid = blockIdx.x;
  const float* W; unsigned short* T; int R, C, idx;
  if (bid < 128)      { W = w0; T = t0; R = 512;  C = 256; idx = bid; }        // 16x8 tiles
  else if (bid < 384) { W = w1; T = t1; R = 1024; C = 256; idx = bid - 128; }  // 32x8
  else                { W = w2; T = t2; R = 1024; C = 128; idx = bid - 384; }  // 32x4
  int ntc = C >> 5;
  int tr = (idx / ntc) << 5;
  int tc = (idx % ntc) << 5;
  int tx = threadIdx.x, ty = threadIdx.y;   // (32,8)
#pragma unroll
  for (int j = ty; j < 32; j += 8)
    tile[j][tx] = W[(size_t)(tr + j) * C + (tc + tx)];
  __syncthreads();
#pragma unroll
  for (int j = ty; j < 32; j += 8)
    T[(size_t)(tc + j) * R + (tr + tx)] = f2bf(tile[tx][j]);
}

// ---------------------------------------------------------------------------
// Kernel 3: bf16 MFMA GEMM, 64x64 C-tile per 256-thread block (4 waves of
// 32x32), BK=32 using mfma_f32_16x16x32_bf16. XOR-swizzled LDS (16B segs) so
// both stores and frag reads are 2-way-or-free on banks. Register prefetch of
// the next K-chunk overlaps global latency with MFMA.
// mode 0: epilogue = +biasmix, ELU, write c-scaled bf16 A_next [M, 4N]
// mode 1: epilogue = +biasmix, write fp32 out [M, N]
// ---------------------------------------------------------------------------
__global__ __launch_bounds__(256) void k_gemm(
    const unsigned short* __restrict__ A,   // M x Kp bf16
    const unsigned short* __restrict__ Wt,  // N x Kp bf16 (transposed weights)
    const float* __restrict__ bias,         // 4 x N fp32
    const float* __restrict__ c,            // M x 4 fp32
    unsigned short* __restrict__ outA,      // mode 0
    float* __restrict__ outF,               // mode 1
    int Kp, int N, int mode) {
  __shared__ __align__(16) unsigned short As[64 * 32];
  __shared__ __align__(16) unsigned short Bs[64 * 32];

  const int tid  = threadIdx.x;
  const int lane = tid & 63;
  const int wid  = tid >> 6;
  const int wr   = (wid >> 1) * 32;   // wave row offset in tile
  const int wc   = (wid & 1) * 32;    // wave col offset in tile
  const int m0   = blockIdx.x * 64;
  const int n0   = blockIdx.y * 64;

  // staging: thread t -> tile row t>>2, 16B segment t&3 (linear global read,
  // swizzled LDS store)
  const int srow = tid >> 2;
  const int sseg = tid & 3;
  const int lds_off = srow * 32 + (((sseg ^ ((srow >> 1) & 3))) << 3);
  const unsigned short* ap = A  + (size_t)(m0 + srow) * Kp + sseg * 8;
  const unsigned short* bp = Wt + (size_t)(n0 + srow) * Kp + sseg * 8;

  f32x4 acc[2][2];
#pragma unroll
  for (int i = 0; i < 2; ++i)
#pragma unroll
    for (int j = 0; j < 2; ++j) acc[i][j] = (f32x4){0.f, 0.f, 0.f, 0.f};

  const int row  = lane & 15;
  const int quad = lane >> 4;

  bf16x8 av = *(const bf16x8*)ap;
  bf16x8 bv = *(const bf16x8*)bp;
  const int nc = Kp >> 5;
  for (int ck = 0; ck < nc; ++ck) {
    __syncthreads();                       // previous chunk's reads done
    *(bf16x8*)&As[lds_off] = av;
    *(bf16x8*)&Bs[lds_off] = bv;
    __syncthreads();
    if (ck + 1 < nc) {                     // prefetch next chunk into regs
      av = *(const bf16x8*)(ap + (ck + 1) * 32);
      bv = *(const bf16x8*)(bp + (ck + 1) * 32);
    }
    bf16x8 af[2], bfr[2];
#pragma unroll
    for (int tm = 0; tm < 2; ++tm) {
      int m = wr + tm * 16 + row;
      af[tm] = *(const bf16x8*)&As[m * 32 + ((quad ^ ((m >> 1) & 3)) << 3)];
    }
#pragma unroll
    for (int tn = 0; tn < 2; ++tn) {
      int n = wc + tn * 16 + row;
      bfr[tn] = *(const bf16x8*)&Bs[n * 32 + ((quad ^ ((n >> 1) & 3)) << 3)];
    }
#pragma unroll
    for (int tm = 0; tm < 2; ++tm)
#pragma unroll
      for (int tn = 0; tn < 2; ++tn)
        acc[tm][tn] = __builtin_amdgcn_mfma_f32_16x16x32_bf16(af[tm], bfr[tn], acc[tm][tn], 0, 0, 0);
  }

  // epilogue: C/D layout col = lane&15, row = quad*4 + reg  (verified m89/m91)
#pragma unroll
  for (int tm = 0; tm < 2; ++tm) {
#pragma unroll
    for (int r = 0; r < 4; ++r) {
      int rg = m0 + wr + tm * 16 + quad * 4 + r;
      f32x4 cb = *(const f32x4*)(c + rg * 4);
#pragma unroll
      for (int tn = 0; tn < 2; ++tn) {
        int cg = n0 + wc + tn * 16 + row;
        float v = acc[tm][tn][r];
        v += cb[0] * bias[cg] + cb[1] * bias[N + cg] +
             cb[2] * bias[2 * N + cg] + cb[3] * bias[3 * N + cg];
        if (mode == 0) {
          float a = v > 0.0f ? v : expm1f(v);   // ELU
          size_t base = (size_t)rg * (4 * N) + cg;
          outA[base]         = f2bf(cb[0] * a);
          outA[base + N]     = f2bf(cb[1] * a);
          outA[base + 2 * N] = f2bf(cb[2] * a);
          outA[base + 3 * N] = f2bf(cb[3] * a);
        } else {
          outF[(size_t)rg * N + cg] = v;
        }
      }
    }
  }
}

// ---------------------------------------------------------------------------
// ws layout (bytes):
//   c    @ 0        : 4096*4*4          = 64 KB
//   Wt0  @ 64K      : 256x512  bf16     = 256 KB
//   Wt1  @ 64K+256K : 256x1024 bf16     = 512 KB
//   Wt2  @ +512K    : 128x1024 bf16     = 256 KB
//   buf0 @ 1114112  : 8 MB  (A0 4096x512 bf16, later reused as A2 4096x1024)
//   A1   @ +8MB     : 8 MB  (4096x1024 bf16)
// total ~17.1 MB
// ---------------------------------------------------------------------------
extern "C" void kernel_launch(void* const* d_in, const int* in_sizes, int n_in,
                              void* d_out, int out_size, void* d_ws, size_t ws_size,
                              hipStream_t stream) {
  const float* x     = (const float*)d_in[0];
  const float* phase = (const float*)d_in[1];
  const float* w0    = (const float*)d_in[2];
  const float* b0    = (const float*)d_in[3];
  const float* w1    = (const float*)d_in[4];
  const float* b1    = (const float*)d_in[5];
  const float* w2    = (const float*)d_in[6];
  const float* b2    = (const float*)d_in[7];
  float* out = (float*)d_out;

  char* ws = (char*)d_ws;
  float* c            = (float*)ws;
  unsigned short* Wt0 = (unsigned short*)(ws + 65536);
  unsigned short* Wt1 = (unsigned short*)(ws + 65536 + 262144);
  unsigned short* Wt2 = (unsigned short*)(ws + 65536 + 262144 + 524288);
  unsigned short* buf0 = (unsigned short*)(ws + 1114112);            // A0 / A2
  unsigned short* A1   = (unsigned short*)(ws + 1114112 + 8388608);

  k_build_a0<<<4096, 128, 0, stream>>>(x, phase, c, buf0);
  k_wt_all<<<512, dim3(32, 8), 0, stream>>>(w0, w1, w2, Wt0, Wt1, Wt2);
  // layer 0: (4096x512)@(512x256) -> A1 (c-scaled bf16, 4096x1024)
  k_gemm<<<dim3(64, 4), 256, 0, stream>>>(buf0, Wt0, b0, c, A1, nullptr, 512, 256, 0);
  // layer 1: (4096x1024)@(1024x256) -> buf0 as A2 (4096x1024)
  k_gemm<<<dim3(64, 4), 256, 0, stream>>>(A1, Wt1, b1, c, buf0, nullptr, 1024, 256, 0);
  // layer 2: (4096x1024)@(1024x128) -> fp32 out
  k_gemm<<<dim3(64, 2), 256, 0, stream>>>(buf0, Wt2, b2, c, nullptr, out, 1024, 128, 1);
}

// Round 2
// 105.993 us; speedup vs baseline: 1.1043x; 1.1043x over previous
//
#include <hip/hip_runtime.h>
#include <hip/hip_bf16.h>
#include <math.h>

// PhaseMLP fully fused: interp-then-matmul == GEMM with c-scaled A:
//   y[b,o] = sum_{k,i} (c_k(b)*x[b,i]) * Wflat[k*K+i, o]
// Layer dependency is PER-ROW, so one block carries its 16 rows through all
// 3 layers with activations living in LDS. 2 launches total:
//   1) weight transpose/convert fp32[4K,O] -> bf16 Wt[O,4K]
//   2) fused 3-layer kernel (256 blocks x 1024 threads = 4 waves/SIMD)

typedef __attribute__((ext_vector_type(8))) short bf16x8;
typedef __attribute__((ext_vector_type(4))) float f32x4;

#define STRIDE 2048  // bytes per LDS A-row: 128 segs x 16B (A0 uses 64 segs)

static __device__ __forceinline__ unsigned short f2bf(float f) {
  union { float f; unsigned int u; } v; v.f = f;
  unsigned int r = v.u + 0x7fffu + ((v.u >> 16) & 1u);  // RNE
  return (unsigned short)(r >> 16);
}

// Catmull-Rom basis coeffs in ABSOLUTE anchor order (c[0..3] for anchors 0..3)
static __device__ __forceinline__ void catmull(float ph, float c[4]) {
  float t = 4.0f * ph;
  float ft = floorf(t);
  int i1 = ((int)ft) & 3;
  float w = t - ft;
  float w2 = w * w, w3 = w2 * w;
  float r0 = -0.5f * w + w2 - 0.5f * w3;
  float r1 = 1.0f - 2.5f * w2 + 1.5f * w3;
  float r2 = 0.5f * w + 2.0f * w2 - 1.5f * w3;
  float r3 = -0.5f * w2 + 0.5f * w3;
  c[(i1 + 3) & 3] = r0;
  c[i1]           = r1;
  c[(i1 + 1) & 3] = r2;
  c[(i1 + 2) & 3] = r3;
}

// ---------------------------------------------------------------------------
// Prep: transpose+convert all three weight tensors (fp32 [4K,O] -> bf16 [O,4K])
// ---------------------------------------------------------------------------
__global__ void k_wt_all(const float* __restrict__ w0, const float* __restrict__ w1,
                         const float* __restrict__ w2, unsigned short* __restrict__ t0,
                         unsigned short* __restrict__ t1, unsigned short* __restrict__ t2) {
  __shared__ float tile[32][33];
  int bid = blockIdx.x;
  const float* W; unsigned short* T; int R, C, idx;
  if (bid < 128)      { W = w0; T = t0; R = 512;  C = 256; idx = bid; }
  else if (bid < 384) { W = w1; T = t1; R = 1024; C = 256; idx = bid - 128; }
  else                { W = w2; T = t2; R = 1024; C = 128; idx = bid - 384; }
  int ntc = C >> 5;
  int tr = (idx / ntc) << 5;
  int tc = (idx % ntc) << 5;
  int tx = threadIdx.x, ty = threadIdx.y;  // (32,8)
#pragma unroll
  for (int j = ty; j < 32; j += 8)
    tile[j][tx] = W[(size_t)(tr + j) * C + (tc + tx)];
  __syncthreads();
#pragma unroll
  for (int j = ty; j < 32; j += 8)
    T[(size_t)(tc + j) * R + (tr + tx)] = f2bf(tile[tx][j]);
}

// ---------------------------------------------------------------------------
// Fused 3-layer kernel. Block = 16 rows, 16 waves (1024 thr).
// A-frag (m=lane&15, k=quad*8+j) from XOR-swizzled LDS; B-frag gathered from
// global Wt (n=lane&15 rows, 16B each) — L2-resident. acc: one 16x16 frag/wave.
// ---------------------------------------------------------------------------
static __device__ __forceinline__ f32x4 gemm_tile(const char* bufIn,
                                                  const unsigned short* __restrict__ Wt,
                                                  int Kp, int colbase, int col, int quad,
                                                  int ck0, int ck1, f32x4 acc) {
  const unsigned short* bp = Wt + (size_t)(colbase + col) * Kp + quad * 8 + ck0 * 32;
  const char* abase = bufIn + col * STRIDE;
  int xr = (col & 7);
#pragma unroll
  for (int ck = ck0; ck < ck1; ++ck) {
    bf16x8 bv = *(const bf16x8*)bp;
    bp += 32;
    int s = ck * 4 + quad;
    bf16x8 av = *(const bf16x8*)(abase + ((s ^ xr) << 4));
    acc = __builtin_amdgcn_mfma_f32_16x16x32_bf16(av, bv, acc, 0, 0, 0);
  }
  return acc;
}

// epilogue for layers 0/1: bias-mix, ELU, write 4 c-scaled bf16 copies to bufOut
static __device__ __forceinline__ void epi_mid(f32x4 acc, const float* __restrict__ bias,
                                               int N, int colg, int quad,
                                               const float cb[4][4], char* bufOut) {
  float bv0 = bias[colg], bv1 = bias[N + colg], bv2 = bias[2 * N + colg],
        bv3 = bias[3 * N + colg];
#pragma unroll
  for (int r = 0; r < 4; ++r) {
    int m = quad * 4 + r;
    float v = acc[r] + cb[r][0] * bv0 + cb[r][1] * bv1 + cb[r][2] * bv2 + cb[r][3] * bv3;
    float a = v > 0.0f ? v : expm1f(v);  // ELU
#pragma unroll
    for (int k = 0; k < 4; ++k) {
      int idx = k * N + colg;
      int s = idx >> 3, j = idx & 7;
      *(unsigned short*)(bufOut + m * STRIDE + ((s ^ (m & 7)) << 4) + j * 2) =
          f2bf(cb[r][k] * a);
    }
  }
}

__global__ __launch_bounds__(1024, 4) void k_fused(
    const float* __restrict__ x, const float* __restrict__ phase,
    const unsigned short* __restrict__ Wt0, const float* __restrict__ b0,
    const unsigned short* __restrict__ Wt1, const float* __restrict__ b1,
    const unsigned short* __restrict__ Wt2, const float* __restrict__ b2,
    float* __restrict__ out) {
  __shared__ __align__(16) char bufA[16 * STRIDE];  // A0 / A2
  __shared__ __align__(16) char bufB[16 * STRIDE];  // A1, then layer-2 reduce buf

  const int tid = threadIdx.x;
  const int lane = tid & 63;
  const int wid = tid >> 6;     // 0..15
  const int col = lane & 15;
  const int quad = lane >> 4;
  const int m0 = blockIdx.x * 16;

  // per-lane Catmull coeffs for its 4 accumulator rows (m = quad*4+r)
  float cb[4][4];
#pragma unroll
  for (int r = 0; r < 4; ++r) catmull(phase[m0 + quad * 4 + r], cb[r]);

  // ---- build A0 (c-scaled bf16 x) into bufA: 16 rows x 64 segs = 1024 thr ----
  {
    int m = tid >> 6;   // row 0..15
    int s = tid & 63;   // 16B segment within row
    float cr[4];
    catmull(phase[m0 + m], cr);
    int kk = s >> 4;
    int i0 = (s & 15) << 3;
    const float* xp = x + (size_t)(m0 + m) * 128 + i0;
    float4 xa = *(const float4*)xp;
    float4 xbv = *(const float4*)(xp + 4);
    float cv = cr[kk];
    bf16x8 v;
    v[0] = (short)f2bf(cv * xa.x);  v[1] = (short)f2bf(cv * xa.y);
    v[2] = (short)f2bf(cv * xa.z);  v[3] = (short)f2bf(cv * xa.w);
    v[4] = (short)f2bf(cv * xbv.x); v[5] = (short)f2bf(cv * xbv.y);
    v[6] = (short)f2bf(cv * xbv.z); v[7] = (short)f2bf(cv * xbv.w);
    *(bf16x8*)(bufA + m * STRIDE + ((s ^ (m & 7)) << 4)) = v;
  }
  __syncthreads();

  // ---- layer 0: bufA (K=512) @ Wt0 -> bufB (A1), all 16 waves, 16 cols each
  {
    f32x4 acc = (f32x4){0.f, 0.f, 0.f, 0.f};
    acc = gemm_tile(bufA, Wt0, 512, wid * 16, col, quad, 0, 16, acc);
    epi_mid(acc, b0, 256, wid * 16 + col, quad, cb, bufB);
  }
  __syncthreads();

  // ---- layer 1: bufB (K=1024) @ Wt1 -> bufA (A2)
  {
    f32x4 acc = (f32x4){0.f, 0.f, 0.f, 0.f};
    acc = gemm_tile(bufB, Wt1, 1024, wid * 16, col, quad, 0, 32, acc);
    epi_mid(acc, b1, 256, wid * 16 + col, quad, cb, bufA);
  }
  __syncthreads();

  // ---- layer 2: bufA (K=1024) @ Wt2 -> out (fp32). N=128: 8 col-groups x 2 k-halves
  {
    int colbase = (wid & 7) * 16;
    int kh = wid >> 3;
    f32x4 acc = (f32x4){0.f, 0.f, 0.f, 0.f};
    acc = gemm_tile(bufA, Wt2, 1024, colbase, col, quad, kh * 16, kh * 16 + 16, acc);

    float* red = (float*)bufB;  // [8][16][17] fp32, overlaid (A1 is dead)
    if (wid >= 8) {
#pragma unroll
      for (int r = 0; r < 4; ++r)
        red[(wid - 8) * 272 + (quad * 4 + r) * 17 + col] = acc[r];
    }
    __syncthreads();
    if (wid < 8) {
      int colg = colbase + col;
      float bv0 = b2[colg], bv1 = b2[128 + colg], bv2 = b2[256 + colg],
            bv3 = b2[384 + colg];
#pragma unroll
      for (int r = 0; r < 4; ++r) {
        float v = acc[r] + red[wid * 272 + (quad * 4 + r) * 17 + col];
        v += cb[r][0] * bv0 + cb[r][1] * bv1 + cb[r][2] * bv2 + cb[r][3] * bv3;
        out[(size_t)(m0 + quad * 4 + r) * 128 + colg] = v;
      }
    }
  }
}

// ---------------------------------------------------------------------------
// ws layout: Wt0 @0 (256KB), Wt1 @256KB (512KB), Wt2 @768KB (256KB). 1 MB.
// ---------------------------------------------------------------------------
extern "C" void kernel_launch(void* const* d_in, const int* in_sizes, int n_in,
                              void* d_out, int out_size, void* d_ws, size_t ws_size,
                              hipStream_t stream) {
  const float* x     = (const float*)d_in[0];
  const float* phase = (const float*)d_in[1];
  const float* w0    = (const float*)d_in[2];
  const float* b0    = (const float*)d_in[3];
  const float* w1    = (const float*)d_in[4];
  const float* b1    = (const float*)d_in[5];
  const float* w2    = (const float*)d_in[6];
  const float* b2    = (const float*)d_in[7];
  float* out = (float*)d_out;

  char* ws = (char*)d_ws;
  unsigned short* Wt0 = (unsigned short*)ws;
  unsigned short* Wt1 = (unsigned short*)(ws + 262144);
  unsigned short* Wt2 = (unsigned short*)(ws + 262144 + 524288);

  k_wt_all<<<512, dim3(32, 8), 0, stream>>>(w0, w1, w2, Wt0, Wt1, Wt2);
  k_fused<<<256, 1024, 0, stream>>>(x, phase, Wt0, b0, Wt1, b1, Wt2, b2, out);
}

// Round 3
// 104.841 us; speedup vs baseline: 1.1165x; 1.0110x over previous
//
#include <hip/hip_runtime.h>
#include <hip/hip_bf16.h>
#include <math.h>

// PhaseMLP fully fused: interp-then-matmul == GEMM with c-scaled A:
//   y[b,o] = sum_{k,i} (c_k(b)*x[b,i]) * Wflat[k*K+i, o]
// Layer dependency is PER-ROW: one block carries its 16 rows through all
// 3 layers, activations in LDS. 2 launches:
//   1) weight transpose/convert fp32[4K,O] -> bf16 Wt[O,4K]
//   2) fused 3-layer kernel (256 blocks x 1024 threads = 4 waves/SIMD)
// R3 change: explicit depth-4 register prefetch pipeline on the B gather
// (R2 left pipelining to the compiler under a 128-VGPR cap -> exposed L2
// latency), fast-ELU via __expf.

typedef __attribute__((ext_vector_type(8))) short bf16x8;
typedef __attribute__((ext_vector_type(4))) float f32x4;

#define STRIDE 2048  // bytes per LDS A-row: 128 segs x 16B (A0 uses 64 segs)

static __device__ __forceinline__ unsigned short f2bf(float f) {
  union { float f; unsigned int u; } v; v.f = f;
  unsigned int r = v.u + 0x7fffu + ((v.u >> 16) & 1u);  // RNE
  return (unsigned short)(r >> 16);
}

// Catmull-Rom basis coeffs in ABSOLUTE anchor order (c[0..3] for anchors 0..3)
static __device__ __forceinline__ void catmull(float ph, float c[4]) {
  float t = 4.0f * ph;
  float ft = floorf(t);
  int i1 = ((int)ft) & 3;
  float w = t - ft;
  float w2 = w * w, w3 = w2 * w;
  float r0 = -0.5f * w + w2 - 0.5f * w3;
  float r1 = 1.0f - 2.5f * w2 + 1.5f * w3;
  float r2 = 0.5f * w + 2.0f * w2 - 1.5f * w3;
  float r3 = -0.5f * w2 + 0.5f * w3;
  c[(i1 + 3) & 3] = r0;
  c[i1]           = r1;
  c[(i1 + 1) & 3] = r2;
  c[(i1 + 2) & 3] = r3;
}

// ---------------------------------------------------------------------------
// Prep: transpose+convert all three weight tensors (fp32 [4K,O] -> bf16 [O,4K])
// ---------------------------------------------------------------------------
__global__ void k_wt_all(const float* __restrict__ w0, const float* __restrict__ w1,
                         const float* __restrict__ w2, unsigned short* __restrict__ t0,
                         unsigned short* __restrict__ t1, unsigned short* __restrict__ t2) {
  __shared__ float tile[32][33];
  int bid = blockIdx.x;
  const float* W; unsigned short* T; int R, C, idx;
  if (bid < 128)      { W = w0; T = t0; R = 512;  C = 256; idx = bid; }
  else if (bid < 384) { W = w1; T = t1; R = 1024; C = 256; idx = bid - 128; }
  else                { W = w2; T = t2; R = 1024; C = 128; idx = bid - 384; }
  int ntc = C >> 5;
  int tr = (idx / ntc) << 5;
  int tc = (idx % ntc) << 5;
  int tx = threadIdx.x, ty = threadIdx.y;  // (32,8)
#pragma unroll
  for (int j = ty; j < 32; j += 8)
    tile[j][tx] = W[(size_t)(tr + j) * C + (tc + tx)];
  __syncthreads();
#pragma unroll
  for (int j = ty; j < 32; j += 8)
    T[(size_t)(tc + j) * R + (tr + tx)] = f2bf(tile[tx][j]);
}

// ---------------------------------------------------------------------------
// Inner GEMM sequence with explicit depth-4 B prefetch pipeline.
// abase = bufIn + col*STRIDE (XOR-swizzled A rows); bp = Wt row base for this
// lane (already offset by quad*8 + ck0*32). nc is compile-time at call sites.
// ---------------------------------------------------------------------------
static __device__ __forceinline__ f32x4 gemm_seq(const char* abase,
                                                 const unsigned short* __restrict__ bp,
                                                 int xr, int quad, int ck0, int nc,
                                                 f32x4 acc) {
  bf16x8 pre[4];
#pragma unroll
  for (int i = 0; i < 4; ++i) pre[i] = *(const bf16x8*)(bp + i * 32);
#pragma unroll
  for (int i = 0; i < nc; ++i) {
    bf16x8 bv = pre[i & 3];
    if (i + 4 < nc) pre[i & 3] = *(const bf16x8*)(bp + (i + 4) * 32);
    int s = (ck0 + i) * 4 + quad;
    bf16x8 av = *(const bf16x8*)(abase + ((s ^ xr) << 4));
    acc = __builtin_amdgcn_mfma_f32_16x16x32_bf16(av, bv, acc, 0, 0, 0);
  }
  return acc;
}

// epilogue for layers 0/1: bias-mix, ELU, write 4 c-scaled bf16 copies to bufOut
static __device__ __forceinline__ void epi_mid(f32x4 acc, const float* __restrict__ bias,
                                               int N, int colg, int quad,
                                               const float cb[4][4], char* bufOut) {
  float bv0 = bias[colg], bv1 = bias[N + colg], bv2 = bias[2 * N + colg],
        bv3 = bias[3 * N + colg];
#pragma unroll
  for (int r = 0; r < 4; ++r) {
    int m = quad * 4 + r;
    float v = acc[r] + cb[r][0] * bv0 + cb[r][1] * bv1 + cb[r][2] * bv2 + cb[r][3] * bv3;
    float a = v > 0.0f ? v : (__expf(v) - 1.0f);  // ELU
#pragma unroll
    for (int k = 0; k < 4; ++k) {
      int idx = k * N + colg;
      int s = idx >> 3, j = idx & 7;
      *(unsigned short*)(bufOut + m * STRIDE + ((s ^ (m & 7)) << 4) + j * 2) =
          f2bf(cb[r][k] * a);
    }
  }
}

__global__ __launch_bounds__(1024, 4) void k_fused(
    const float* __restrict__ x, const float* __restrict__ phase,
    const unsigned short* __restrict__ Wt0, const float* __restrict__ b0,
    const unsigned short* __restrict__ Wt1, const float* __restrict__ b1,
    const unsigned short* __restrict__ Wt2, const float* __restrict__ b2,
    float* __restrict__ out) {
  __shared__ __align__(16) char bufA[16 * STRIDE];  // A0 / A2
  __shared__ __align__(16) char bufB[16 * STRIDE];  // A1, then layer-2 reduce buf

  const int tid = threadIdx.x;
  const int lane = tid & 63;
  const int wid = tid >> 6;     // 0..15
  const int col = lane & 15;
  const int quad = lane >> 4;
  const int xr = col & 7;
  const int m0 = blockIdx.x * 16;

  // per-lane Catmull coeffs for its 4 accumulator rows (m = quad*4+r)
  float cb[4][4];
#pragma unroll
  for (int r = 0; r < 4; ++r) catmull(phase[m0 + quad * 4 + r], cb[r]);

  // ---- build A0 (c-scaled bf16 x) into bufA: 16 rows x 64 segs = 1024 thr ----
  {
    int m = tid >> 6;   // row 0..15
    int s = tid & 63;   // 16B segment within row
    float cr[4];
    catmull(phase[m0 + m], cr);
    int kk = s >> 4;
    int i0 = (s & 15) << 3;
    const float* xp = x + (size_t)(m0 + m) * 128 + i0;
    float4 xa = *(const float4*)xp;
    float4 xbv = *(const float4*)(xp + 4);
    float cv = cr[kk];
    bf16x8 v;
    v[0] = (short)f2bf(cv * xa.x);  v[1] = (short)f2bf(cv * xa.y);
    v[2] = (short)f2bf(cv * xa.z);  v[3] = (short)f2bf(cv * xa.w);
    v[4] = (short)f2bf(cv * xbv.x); v[5] = (short)f2bf(cv * xbv.y);
    v[6] = (short)f2bf(cv * xbv.z); v[7] = (short)f2bf(cv * xbv.w);
    *(bf16x8*)(bufA + m * STRIDE + ((s ^ (m & 7)) << 4)) = v;
  }
  __syncthreads();

  // ---- layer 0: bufA (K=512) @ Wt0 -> bufB (A1), 16 waves x 16 cols
  {
    f32x4 acc = (f32x4){0.f, 0.f, 0.f, 0.f};
    acc = gemm_seq(bufA + col * STRIDE, Wt0 + (size_t)(wid * 16 + col) * 512 + quad * 8,
                   xr, quad, 0, 16, acc);
    epi_mid(acc, b0, 256, wid * 16 + col, quad, cb, bufB);
  }
  __syncthreads();

  // ---- layer 1: bufB (K=1024) @ Wt1 -> bufA (A2)
  {
    f32x4 acc = (f32x4){0.f, 0.f, 0.f, 0.f};
    acc = gemm_seq(bufB + col * STRIDE, Wt1 + (size_t)(wid * 16 + col) * 1024 + quad * 8,
                   xr, quad, 0, 32, acc);
    epi_mid(acc, b1, 256, wid * 16 + col, quad, cb, bufA);
  }
  __syncthreads();

  // ---- layer 2: bufA (K=1024) @ Wt2 -> out fp32. N=128: 8 col-grps x 2 k-halves
  {
    int colbase = (wid & 7) * 16;
    int kh = wid >> 3;
    f32x4 acc = (f32x4){0.f, 0.f, 0.f, 0.f};
    acc = gemm_seq(bufA + col * STRIDE,
                   Wt2 + (size_t)(colbase + col) * 1024 + quad * 8 + kh * 512,
                   xr, quad, kh * 16, 16, acc);

    float* red = (float*)bufB;  // [8][16][17] fp32, overlaid (A1 is dead)
    if (wid >= 8) {
#pragma unroll
      for (int r = 0; r < 4; ++r)
        red[(wid - 8) * 272 + (quad * 4 + r) * 17 + col] = acc[r];
    }
    __syncthreads();
    if (wid < 8) {
      int colg = colbase + col;
      float bv0 = b2[colg], bv1 = b2[128 + colg], bv2 = b2[256 + colg],
            bv3 = b2[384 + colg];
#pragma unroll
      for (int r = 0; r < 4; ++r) {
        float v = acc[r] + red[wid * 272 + (quad * 4 + r) * 17 + col];
        v += cb[r][0] * bv0 + cb[r][1] * bv1 + cb[r][2] * bv2 + cb[r][3] * bv3;
        out[(size_t)(m0 + quad * 4 + r) * 128 + colg] = v;
      }
    }
  }
}

// ---------------------------------------------------------------------------
// ws layout: Wt0 @0 (256KB), Wt1 @256KB (512KB), Wt2 @768KB (256KB). 1 MB.
// ---------------------------------------------------------------------------
extern "C" void kernel_launch(void* const* d_in, const int* in_sizes, int n_in,
                              void* d_out, int out_size, void* d_ws, size_t ws_size,
                              hipStream_t stream) {
  const float* x     = (const float*)d_in[0];
  const float* phase = (const float*)d_in[1];
  const float* w0    = (const float*)d_in[2];
  const float* b0    = (const float*)d_in[3];
  const float* w1    = (const float*)d_in[4];
  const float* b1    = (const float*)d_in[5];
  const float* w2    = (const float*)d_in[6];
  const float* b2    = (const float*)d_in[7];
  float* out = (float*)d_out;

  char* ws = (char*)d_ws;
  unsigned short* Wt0 = (unsigned short*)ws;
  unsigned short* Wt1 = (unsigned short*)(ws + 262144);
  unsigned short* Wt2 = (unsigned short*)(ws + 262144 + 524288);

  k_wt_all<<<512, dim3(32, 8), 0, stream>>>(w0, w1, w2, Wt0, Wt1, Wt2);
  k_fused<<<256, 1024, 0, stream>>>(x, phase, Wt0, b0, Wt1, b1, Wt2, b2, out);
}